// Round 1
// baseline (298.832 us; speedup 1.0000x reference)
//
#include <hip/hip_runtime.h>
#include <stdint.h>

#define B_ 2
#define T_ 2048
#define C_ 1024
#define H_ 16
#define D_ 64
#define M_ (B_*T_)

typedef __bf16 bf16x8 __attribute__((ext_vector_type(8)));
typedef float f32x4 __attribute__((ext_vector_type(4)));

static __device__ __forceinline__ unsigned short f32_bf16(float f) {
    unsigned int u = __float_as_uint(f);
    u += 0x7FFFu + ((u >> 16) & 1u);   // round-to-nearest-even
    return (unsigned short)(u >> 16);
}

// ---------------- cast f32 -> bf16 (vectorized) ----------------
__global__ void cast_kernel(const float* __restrict__ in, unsigned short* __restrict__ out, int n) {
    int i = (blockIdx.x * 256 + threadIdx.x) * 4;
    if (i >= n) return;
    float4 f = *(const float4*)(in + i);
    ushort4 o;
    o.x = f32_bf16(f.x); o.y = f32_bf16(f.y); o.z = f32_bf16(f.z); o.w = f32_bf16(f.w);
    *(ushort4*)(out + i) = o;
}

// ---------------- transpose+cast: W [K][N] f32 -> Wt [N][K] bf16 ----------------
__global__ void transpose_cast_kernel(const float* __restrict__ W, unsigned short* __restrict__ Wt,
                                      int K, int N) {
    __shared__ float tile[32][33];
    int n0 = blockIdx.x * 32, k0 = blockIdx.y * 32;
    int tx = threadIdx.x, ty = threadIdx.y;
    #pragma unroll
    for (int j = 0; j < 32; j += 8)
        tile[ty + j][tx] = W[(size_t)(k0 + ty + j) * N + n0 + tx];
    __syncthreads();
    #pragma unroll
    for (int j = 0; j < 32; j += 8)
        Wt[(size_t)(n0 + ty + j) * K + k0 + tx] = f32_bf16(tile[tx][ty + j]);
}

// ---------------- GEMM: C[M][N] = A[M][K](bf16) * Bt[N][K]^T(bf16) + bias ----------------
// 128x128 tile, BK=32, 4 waves (2x2), each wave 64x64 via 4x4 frags of 16x16x32 MFMA.
// EPI=0: scatter bf16 into qkv [3][B*H][T][D].  EPI=1: write f32 to out [M][N].
template<int EPI>
__global__ __launch_bounds__(256) void gemm_bt(
    const unsigned short* __restrict__ A,
    const unsigned short* __restrict__ Bt,
    const float* __restrict__ bias,
    unsigned short* __restrict__ out_bf16,
    float* __restrict__ out_f32,
    int M, int N, int K)
{
    __shared__ unsigned short As[128 * 40];   // pad 32 -> 40 elems (80B rows, 2-way banks)
    __shared__ unsigned short Bs[128 * 40];
    int tid = threadIdx.x;
    int lane = tid & 63, wid = tid >> 6;
    int fr = lane & 15, fg = lane >> 4;
    int row0 = blockIdx.x * 128, col0 = blockIdx.y * 128;
    int wm = (wid >> 1) * 64, wn = (wid & 1) * 64;

    f32x4 acc[4][4];
    #pragma unroll
    for (int i = 0; i < 4; ++i)
        #pragma unroll
        for (int j = 0; j < 4; ++j)
            acc[i][j] = (f32x4){0.f, 0.f, 0.f, 0.f};

    int sr = tid >> 2, sc = (tid & 3) << 3;   // stage: row, col-chunk(8 bf16)

    for (int k0 = 0; k0 < K; k0 += 32) {
        uint4 a0 = *(const uint4*)(A  + (size_t)(row0 + sr)      * K + k0 + sc);
        uint4 a1 = *(const uint4*)(A  + (size_t)(row0 + sr + 64) * K + k0 + sc);
        uint4 b0 = *(const uint4*)(Bt + (size_t)(col0 + sr)      * K + k0 + sc);
        uint4 b1 = *(const uint4*)(Bt + (size_t)(col0 + sr + 64) * K + k0 + sc);
        __syncthreads();                       // prev compute done before overwrite
        *(uint4*)(As + sr * 40 + sc)        = a0;
        *(uint4*)(As + (sr + 64) * 40 + sc) = a1;
        *(uint4*)(Bs + sr * 40 + sc)        = b0;
        *(uint4*)(Bs + (sr + 64) * 40 + sc) = b1;
        __syncthreads();

        bf16x8 af[4], bf[4];
        #pragma unroll
        for (int i = 0; i < 4; ++i) {
            af[i] = *(const bf16x8*)(As + (wm + i * 16 + fr) * 40 + fg * 8);
            bf[i] = *(const bf16x8*)(Bs + (wn + i * 16 + fr) * 40 + fg * 8);
        }
        #pragma unroll
        for (int mi = 0; mi < 4; ++mi)
            #pragma unroll
            for (int ni = 0; ni < 4; ++ni)
                acc[mi][ni] = __builtin_amdgcn_mfma_f32_16x16x32_bf16(af[mi], bf[ni], acc[mi][ni], 0, 0, 0);
    }

    #pragma unroll
    for (int mi = 0; mi < 4; ++mi) {
        int rowb = row0 + wm + mi * 16 + fg * 4;
        #pragma unroll
        for (int ni = 0; ni < 4; ++ni) {
            int col = col0 + wn + ni * 16 + fr;
            float bv = bias[col];
            #pragma unroll
            for (int r = 0; r < 4; ++r) {
                float v = acc[mi][ni][r] + bv;
                int rr = rowb + r;
                if (EPI == 0) {
                    int part = col >> 10, c = col & 1023;
                    int h = c >> 6, d = c & 63;
                    int b = rr >> 11, t = rr & 2047;
                    out_bf16[(size_t)part * (B_ * H_ * T_ * D_) +
                             (size_t)((b * H_ + h) * T_ + t) * D_ + d] = f32_bf16(v);
                } else {
                    out_f32[(size_t)rr * N + col] = v;
                }
            }
        }
    }
}

// ---------------- causal flash attention ----------------
// grid: (T/64, B*H). block 256 = 4 waves; wave w owns Q rows [qb*64+16w, +16).
// KV tiles of 32; K,V staged in LDS; P re-fragmented through per-wave LDS.
__global__ __launch_bounds__(256) void attn_kernel(
    const unsigned short* __restrict__ qg,
    const unsigned short* __restrict__ kg,
    const unsigned short* __restrict__ vg,
    unsigned short* __restrict__ y)
{
    int qb = blockIdx.x;
    int bh = blockIdx.y;
    int b = bh >> 4, h = bh & 15;
    int tid = threadIdx.x, wid = tid >> 6, lane = tid & 63;
    int fr = lane & 15, fg = lane >> 4;

    const unsigned short* qp = qg + (size_t)bh * T_ * D_;
    const unsigned short* kp = kg + (size_t)bh * T_ * D_;
    const unsigned short* vp = vg + (size_t)bh * T_ * D_;

    __shared__ unsigned short Ks[32 * 72];    // [kv][d], stride 72 (144B)
    __shared__ unsigned short Vs[64 * 40];    // [d][kv], stride 40 (80B)
    __shared__ unsigned short Ps[4][16 * 40]; // per-wave P [q][kv]

    int qrow = qb * 64 + wid * 16 + fr;
    bf16x8 qf0 = *(const bf16x8*)(qp + qrow * 64 + fg * 8);
    bf16x8 qf1 = *(const bf16x8*)(qp + qrow * 64 + 32 + fg * 8);

    f32x4 oacc[4];
    #pragma unroll
    for (int i = 0; i < 4; ++i) oacc[i] = (f32x4){0.f, 0.f, 0.f, 0.f};
    float m_run[4], l_run[4];
    #pragma unroll
    for (int r = 0; r < 4; ++r) { m_run[r] = -1e30f; l_run[r] = 0.f; }

    int svr = tid >> 3, svc = (tid & 7) << 3; // stage: kv row, d chunk
    unsigned short* Pw = Ps[wid];

    int ntiles = qb * 2 + 2;
    for (int t = 0; t < ntiles; ++t) {
        int kv0 = t * 32;
        uint4 kd = *(const uint4*)(kp + (size_t)(kv0 + svr) * 64 + svc);
        uint4 vd = *(const uint4*)(vp + (size_t)(kv0 + svr) * 64 + svc);
        __syncthreads();
        *(uint4*)(Ks + svr * 72 + svc) = kd;
        unsigned short vv[8];
        *(uint4*)vv = vd;
        #pragma unroll
        for (int i = 0; i < 8; ++i)
            Vs[(svc + i) * 40 + svr] = vv[i];   // transpose V into [d][kv]
        __syncthreads();

        // S = Q K^T  (16q x 32kv per wave)
        f32x4 s0 = (f32x4){0.f,0.f,0.f,0.f}, s1 = (f32x4){0.f,0.f,0.f,0.f};
        #pragma unroll
        for (int ks = 0; ks < 2; ++ks) {
            bf16x8 kf0 = *(const bf16x8*)(Ks + fr        * 72 + ks * 32 + fg * 8);
            bf16x8 kf1 = *(const bf16x8*)(Ks + (16 + fr) * 72 + ks * 32 + fg * 8);
            bf16x8 qq  = ks ? qf1 : qf0;
            s0 = __builtin_amdgcn_mfma_f32_16x16x32_bf16(qq, kf0, s0, 0, 0, 0);
            s1 = __builtin_amdgcn_mfma_f32_16x16x32_bf16(qq, kf1, s1, 0, 0, 0);
        }

        // online softmax (rows owned: fg*4 + r)
        int rowg = qb * 64 + wid * 16 + fg * 4;
        #pragma unroll
        for (int r = 0; r < 4; ++r) {
            int rg = rowg + r;
            float v0 = (kv0 + fr)      <= rg ? s0[r] * 0.125f : -1e30f;
            float v1 = (kv0 + 16 + fr) <= rg ? s1[r] * 0.125f : -1e30f;
            float rm = fmaxf(v0, v1);
            rm = fmaxf(rm, __shfl_xor(rm, 1));
            rm = fmaxf(rm, __shfl_xor(rm, 2));
            rm = fmaxf(rm, __shfl_xor(rm, 4));
            rm = fmaxf(rm, __shfl_xor(rm, 8));
            float mnew = fmaxf(m_run[r], rm);
            float p0 = __expf(v0 - mnew);
            float p1 = __expf(v1 - mnew);
            float rs = p0 + p1;
            rs += __shfl_xor(rs, 1);
            rs += __shfl_xor(rs, 2);
            rs += __shfl_xor(rs, 4);
            rs += __shfl_xor(rs, 8);
            float ex = __expf(m_run[r] - mnew);
            l_run[r] = l_run[r] * ex + rs;
            m_run[r] = mnew;
            #pragma unroll
            for (int ni = 0; ni < 4; ++ni) oacc[ni][r] *= ex;
            Pw[(fg * 4 + r) * 40 + fr]      = f32_bf16(p0);
            Pw[(fg * 4 + r) * 40 + 16 + fr] = f32_bf16(p1);
        }
        asm volatile("s_waitcnt lgkmcnt(0)" ::: "memory");

        // O += P V   (A-frag of P: row=fr, k=fg*8+i; B-frag of V from Vs[d][kv])
        bf16x8 pa = *(const bf16x8*)(Pw + fr * 40 + fg * 8);
        #pragma unroll
        for (int ni = 0; ni < 4; ++ni) {
            bf16x8 vf = *(const bf16x8*)(Vs + (ni * 16 + fr) * 40 + fg * 8);
            oacc[ni] = __builtin_amdgcn_mfma_f32_16x16x32_bf16(pa, vf, oacc[ni], 0, 0, 0);
        }
    }

    // epilogue: O / l -> y[b][t][h*64+d] (bf16)
    #pragma unroll
    for (int r = 0; r < 4; ++r) {
        float inv = 1.f / l_run[r];
        int trow = qb * 64 + wid * 16 + fg * 4 + r;
        #pragma unroll
        for (int ni = 0; ni < 4; ++ni) {
            int col = h * 64 + ni * 16 + fr;
            y[((size_t)b * T_ + trow) * C_ + col] = f32_bf16(oacc[ni][r] * inv);
        }
    }
}

// ---------------- launch ----------------
extern "C" void kernel_launch(void* const* d_in, const int* in_sizes, int n_in,
                              void* d_out, int out_size, void* d_ws, size_t ws_size,
                              hipStream_t stream) {
    const float* x     = (const float*)d_in[0];
    const float* Wqkv  = (const float*)d_in[1];
    const float* bqkv  = (const float*)d_in[2];
    const float* Wproj = (const float*)d_in[3];
    const float* bproj = (const float*)d_in[4];
    float* out = (float*)d_out;

    char* ws = (char*)d_ws;
    unsigned short* x_bf    = (unsigned short*)(ws);                 //  8 MB
    unsigned short* wqkv_t  = (unsigned short*)(ws + 8388608);       //  6 MB
    unsigned short* wproj_t = (unsigned short*)(ws + 14680064);      //  2 MB
    unsigned short* qkv     = (unsigned short*)(ws + 16777216);      // 24 MB [3][B*H][T][D]
    unsigned short* ybuf    = (unsigned short*)(ws + 41943040);      //  8 MB

    cast_kernel<<<(M_ * C_) / 4 / 256, 256, 0, stream>>>(x, x_bf, M_ * C_);
    transpose_cast_kernel<<<dim3(3072 / 32, 1024 / 32), dim3(32, 8), 0, stream>>>(Wqkv, wqkv_t, 1024, 3072);
    transpose_cast_kernel<<<dim3(1024 / 32, 1024 / 32), dim3(32, 8), 0, stream>>>(Wproj, wproj_t, 1024, 1024);

    gemm_bt<0><<<dim3(M_ / 128, 3072 / 128), 256, 0, stream>>>(
        x_bf, wqkv_t, bqkv, qkv, nullptr, M_, 3072, 1024);

    attn_kernel<<<dim3(T_ / 64, B_ * H_), 256, 0, stream>>>(
        qkv, qkv + (size_t)B_ * H_ * T_ * D_, qkv + 2 * (size_t)B_ * H_ * T_ * D_, ybuf);

    gemm_bt<1><<<dim3(M_ / 128, 1024 / 128), 256, 0, stream>>>(
        ybuf, wproj_t, bproj, nullptr, out, M_, 1024, 1024);
}

// Round 2
// 290.795 us; speedup vs baseline: 1.0276x; 1.0276x over previous
//
#include <hip/hip_runtime.h>
#include <stdint.h>

#define B_ 2
#define T_ 2048
#define C_ 1024
#define H_ 16
#define D_ 64
#define M_ (B_*T_)
#define BHTD_ (B_*H_*T_*D_)

typedef __bf16 bf16x8 __attribute__((ext_vector_type(8)));
typedef float f32x4 __attribute__((ext_vector_type(4)));

static __device__ __forceinline__ unsigned short f32_bf16(float f) {
    unsigned int u = __float_as_uint(f);
    u += 0x7FFFu + ((u >> 16) & 1u);   // round-to-nearest-even
    return (unsigned short)(u >> 16);
}

// ---------------- cast f32 -> bf16 (vectorized) ----------------
__global__ void cast_kernel(const float* __restrict__ in, unsigned short* __restrict__ out, int n) {
    int i = (blockIdx.x * 256 + threadIdx.x) * 4;
    if (i >= n) return;
    float4 f = *(const float4*)(in + i);
    ushort4 o;
    o.x = f32_bf16(f.x); o.y = f32_bf16(f.y); o.z = f32_bf16(f.z); o.w = f32_bf16(f.w);
    *(ushort4*)(out + i) = o;
}

// ---------------- transpose+cast: W [K][N] f32 -> Wt [N][K] bf16 ----------------
__global__ void transpose_cast_kernel(const float* __restrict__ W, unsigned short* __restrict__ Wt,
                                      int K, int N) {
    __shared__ float tile[32][33];
    int n0 = blockIdx.x * 32, k0 = blockIdx.y * 32;
    int tx = threadIdx.x, ty = threadIdx.y;
    #pragma unroll
    for (int j = 0; j < 32; j += 8)
        tile[ty + j][tx] = W[(size_t)(k0 + ty + j) * N + n0 + tx];
    __syncthreads();
    #pragma unroll
    for (int j = 0; j < 32; j += 8)
        Wt[(size_t)(n0 + ty + j) * K + k0 + tx] = f32_bf16(tile[tx][ty + j]);
}

// ---------------- GEMM: C[M][N] = A[M][K](bf16) * Bt[N][K]^T(bf16) + bias ----------------
// EPI=0: scatter bf16 into qkv; q,k as [bh][T][D], v as [bh][D][T] (transposed).
// EPI=1: write f32 to out [M][N].
template<int EPI>
__global__ __launch_bounds__(256) void gemm_bt(
    const unsigned short* __restrict__ A,
    const unsigned short* __restrict__ Bt,
    const float* __restrict__ bias,
    unsigned short* __restrict__ out_bf16,
    float* __restrict__ out_f32,
    int M, int N, int K)
{
    __shared__ unsigned short As[128 * 40];
    __shared__ unsigned short Bs[128 * 40];
    int tid = threadIdx.x;
    int lane = tid & 63, wid = tid >> 6;
    int fr = lane & 15, fg = lane >> 4;
    int row0 = blockIdx.x * 128, col0 = blockIdx.y * 128;
    int wm = (wid >> 1) * 64, wn = (wid & 1) * 64;

    f32x4 acc[4][4];
    #pragma unroll
    for (int i = 0; i < 4; ++i)
        #pragma unroll
        for (int j = 0; j < 4; ++j)
            acc[i][j] = (f32x4){0.f, 0.f, 0.f, 0.f};

    int sr = tid >> 2, sc = (tid & 3) << 3;

    for (int k0 = 0; k0 < K; k0 += 32) {
        uint4 a0 = *(const uint4*)(A  + (size_t)(row0 + sr)      * K + k0 + sc);
        uint4 a1 = *(const uint4*)(A  + (size_t)(row0 + sr + 64) * K + k0 + sc);
        uint4 b0 = *(const uint4*)(Bt + (size_t)(col0 + sr)      * K + k0 + sc);
        uint4 b1 = *(const uint4*)(Bt + (size_t)(col0 + sr + 64) * K + k0 + sc);
        __syncthreads();
        *(uint4*)(As + sr * 40 + sc)        = a0;
        *(uint4*)(As + (sr + 64) * 40 + sc) = a1;
        *(uint4*)(Bs + sr * 40 + sc)        = b0;
        *(uint4*)(Bs + (sr + 64) * 40 + sc) = b1;
        __syncthreads();

        bf16x8 af[4], bfr[4];
        #pragma unroll
        for (int i = 0; i < 4; ++i) {
            af[i]  = *(const bf16x8*)(As + (wm + i * 16 + fr) * 40 + fg * 8);
            bfr[i] = *(const bf16x8*)(Bs + (wn + i * 16 + fr) * 40 + fg * 8);
        }
        #pragma unroll
        for (int mi = 0; mi < 4; ++mi)
            #pragma unroll
            for (int ni = 0; ni < 4; ++ni)
                acc[mi][ni] = __builtin_amdgcn_mfma_f32_16x16x32_bf16(af[mi], bfr[ni], acc[mi][ni], 0, 0, 0);
    }

    #pragma unroll
    for (int mi = 0; mi < 4; ++mi) {
        int rowb = row0 + wm + mi * 16 + fg * 4;
        #pragma unroll
        for (int ni = 0; ni < 4; ++ni) {
            int col = col0 + wn + ni * 16 + fr;
            float bv = bias[col];
            #pragma unroll
            for (int r = 0; r < 4; ++r) {
                float v = acc[mi][ni][r] + bv;
                int rr = rowb + r;
                if (EPI == 0) {
                    int part = col >> 10, c = col & 1023;
                    int h = c >> 6, d = c & 63;
                    int b = rr >> 11, t = rr & 2047;
                    size_t idx;
                    if (part == 2)
                        idx = (size_t)2 * BHTD_ + ((size_t)(b * H_ + h) * D_ + d) * T_ + t;
                    else
                        idx = (size_t)part * BHTD_ + ((size_t)(b * H_ + h) * T_ + t) * D_ + d;
                    out_bf16[idx] = f32_bf16(v);
                } else {
                    out_f32[(size_t)rr * N + col] = v;
                }
            }
        }
    }
}

// ---------------- causal flash attention v2 ----------------
// grid (T/128, B*H), block 256 = 4 waves. Wave w owns 32 q rows. KVBLK=64.
// No K/V LDS staging (global reads, L1/L2-cached), no __syncthreads.
// P routed through per-wave XOR-swizzled LDS.
__global__ __launch_bounds__(256) void attn_kernel(
    const unsigned short* __restrict__ qg,
    const unsigned short* __restrict__ kg,
    const unsigned short* __restrict__ vtg,  // [bh][D][T]
    unsigned short* __restrict__ y)
{
    const int qb = gridDim.x - 1 - blockIdx.x;   // heavy blocks first
    const int bh = blockIdx.y;
    const int b = bh >> 4, h = bh & 15;
    const int tid = threadIdx.x, wid = tid >> 6, lane = tid & 63;
    const int fr = lane & 15, fg = lane >> 4;

    const unsigned short* qp = qg + (size_t)bh * (T_ * D_);
    const unsigned short* kp = kg + (size_t)bh * (T_ * D_);
    const unsigned short* vp = vtg + (size_t)bh * (D_ * T_);

    __shared__ unsigned short Ps[4][32 * 64];    // per-wave P tile [32 q][64 kv], swizzled
    char* Pw = (char*)Ps[wid];

    const int r0 = qb * 128 + wid * 32;

    // Q fragments (held in registers for the whole kernel)
    bf16x8 qf[2][2];
    #pragma unroll
    for (int m = 0; m < 2; ++m)
        #pragma unroll
        for (int kd = 0; kd < 2; ++kd)
            qf[m][kd] = *(const bf16x8*)(qp + (size_t)(r0 + m * 16 + fr) * D_ + kd * 32 + fg * 8);

    f32x4 o[2][4];
    float mrun[2][4], lrun[2][4];
    #pragma unroll
    for (int m = 0; m < 2; ++m)
        #pragma unroll
        for (int n = 0; n < 4; ++n) o[m][n] = (f32x4){0.f, 0.f, 0.f, 0.f};
    #pragma unroll
    for (int m = 0; m < 2; ++m)
        #pragma unroll
        for (int r = 0; r < 4; ++r) { mrun[m][r] = -1e30f; lrun[m][r] = 0.f; }

    const float SC = 0.18033688011112042f;  // log2(e) / sqrt(D)

    const int nt = (r0 + 95) >> 6;           // per-wave causal tile count
    for (int t = 0; t < nt; ++t) {
        const int kv0 = t * 64;

        // S = Q K^T : K B-frags straight from global [bh][T][D]
        f32x4 s[2][4];
        #pragma unroll
        for (int m = 0; m < 2; ++m)
            #pragma unroll
            for (int n = 0; n < 4; ++n) s[m][n] = (f32x4){0.f, 0.f, 0.f, 0.f};
        #pragma unroll
        for (int kd = 0; kd < 2; ++kd) {
            bf16x8 kf[4];
            #pragma unroll
            for (int n = 0; n < 4; ++n)
                kf[n] = *(const bf16x8*)(kp + (size_t)(kv0 + n * 16 + fr) * D_ + kd * 32 + fg * 8);
            #pragma unroll
            for (int m = 0; m < 2; ++m)
                #pragma unroll
                for (int n = 0; n < 4; ++n)
                    s[m][n] = __builtin_amdgcn_mfma_f32_16x16x32_bf16(qf[m][kd], kf[n], s[m][n], 0, 0, 0);
        }

        // prefetch V^T B-frags (global [bh][D][T], contiguous along kv)
        bf16x8 vf[4][2];
        #pragma unroll
        for (int nd = 0; nd < 4; ++nd)
            #pragma unroll
            for (int kk = 0; kk < 2; ++kk)
                vf[nd][kk] = *(const bf16x8*)(vp + (size_t)(nd * 16 + fr) * T_ + kv0 + kk * 32 + fg * 8);

        const bool masked = (kv0 + 63 > r0);   // wave-uniform: only diagonal tile
        #pragma unroll
        for (int m = 0; m < 2; ++m) {
            #pragma unroll
            for (int r = 0; r < 4; ++r) {
                const int row = m * 16 + fg * 4 + r;
                float x0 = s[m][0][r] * SC, x1 = s[m][1][r] * SC;
                float x2 = s[m][2][r] * SC, x3 = s[m][3][r] * SC;
                if (masked) {
                    const int rg = r0 + row;
                    if (kv0 +      fr > rg) x0 = -1e30f;
                    if (kv0 + 16 + fr > rg) x1 = -1e30f;
                    if (kv0 + 32 + fr > rg) x2 = -1e30f;
                    if (kv0 + 48 + fr > rg) x3 = -1e30f;
                }
                float rm = fmaxf(fmaxf(x0, x1), fmaxf(x2, x3));
                rm = fmaxf(rm, __shfl_xor(rm, 1));
                rm = fmaxf(rm, __shfl_xor(rm, 2));
                rm = fmaxf(rm, __shfl_xor(rm, 4));
                rm = fmaxf(rm, __shfl_xor(rm, 8));
                const float mold = mrun[m][r];
                const float mnew = fmaxf(mold, rm);
                const float p0 = exp2f(x0 - mnew);
                const float p1 = exp2f(x1 - mnew);
                const float p2 = exp2f(x2 - mnew);
                const float p3 = exp2f(x3 - mnew);
                const float ex = exp2f(mold - mnew);
                lrun[m][r] = lrun[m][r] * ex + (p0 + p1) + (p2 + p3);  // per-lane partial
                mrun[m][r] = mnew;
                #pragma unroll
                for (int nd = 0; nd < 4; ++nd) o[m][nd][r] *= ex;
                const unsigned swz = (unsigned)((row & 7) << 4);
                const unsigned rb = (unsigned)row * 128 + (unsigned)fr * 2;
                *(unsigned short*)(Pw + ((rb +  0) ^ swz)) = f32_bf16(p0);
                *(unsigned short*)(Pw + ((rb + 32) ^ swz)) = f32_bf16(p1);
                *(unsigned short*)(Pw + ((rb + 64) ^ swz)) = f32_bf16(p2);
                *(unsigned short*)(Pw + ((rb + 96) ^ swz)) = f32_bf16(p3);
            }
        }
        asm volatile("s_waitcnt lgkmcnt(0)" ::: "memory");
        __builtin_amdgcn_sched_barrier(0);

        // O += P V : P A-frags from swizzled LDS, V^T frags already in regs
        #pragma unroll
        for (int m = 0; m < 2; ++m) {
            const unsigned swz = (unsigned)((fr & 7) << 4);
            const unsigned rowb = (unsigned)(m * 16 + fr) * 128;
            #pragma unroll
            for (int kk = 0; kk < 2; ++kk) {
                bf16x8 pa = *(const bf16x8*)(Pw + ((rowb + kk * 64 + fg * 16) ^ swz));
                #pragma unroll
                for (int nd = 0; nd < 4; ++nd)
                    o[m][nd] = __builtin_amdgcn_mfma_f32_16x16x32_bf16(pa, vf[nd][kk], o[m][nd], 0, 0, 0);
            }
        }
    }

    // epilogue: reduce l across fr lanes, normalize, store bf16 y[b][t][h*64+d]
    #pragma unroll
    for (int m = 0; m < 2; ++m)
        #pragma unroll
        for (int r = 0; r < 4; ++r) {
            float rs = lrun[m][r];
            rs += __shfl_xor(rs, 1);
            rs += __shfl_xor(rs, 2);
            rs += __shfl_xor(rs, 4);
            rs += __shfl_xor(rs, 8);
            const float inv = 1.f / rs;
            const int trow = r0 + m * 16 + fg * 4 + r;
            #pragma unroll
            for (int nd = 0; nd < 4; ++nd)
                y[((size_t)b * T_ + trow) * C_ + h * 64 + nd * 16 + fr] =
                    f32_bf16(o[m][nd][r] * inv);
        }
}

// ---------------- launch ----------------
extern "C" void kernel_launch(void* const* d_in, const int* in_sizes, int n_in,
                              void* d_out, int out_size, void* d_ws, size_t ws_size,
                              hipStream_t stream) {
    const float* x     = (const float*)d_in[0];
    const float* Wqkv  = (const float*)d_in[1];
    const float* bqkv  = (const float*)d_in[2];
    const float* Wproj = (const float*)d_in[3];
    const float* bproj = (const float*)d_in[4];
    float* out = (float*)d_out;

    char* ws = (char*)d_ws;
    unsigned short* x_bf    = (unsigned short*)(ws);                 //  8 MB
    unsigned short* wqkv_t  = (unsigned short*)(ws + 8388608);       //  6 MB
    unsigned short* wproj_t = (unsigned short*)(ws + 14680064);      //  2 MB
    unsigned short* qkv     = (unsigned short*)(ws + 16777216);      // 24 MB
    unsigned short* ybuf    = (unsigned short*)(ws + 41943040);      //  8 MB

    cast_kernel<<<(M_ * C_) / 4 / 256, 256, 0, stream>>>(x, x_bf, M_ * C_);
    transpose_cast_kernel<<<dim3(3072 / 32, 1024 / 32), dim3(32, 8), 0, stream>>>(Wqkv, wqkv_t, 1024, 3072);
    transpose_cast_kernel<<<dim3(1024 / 32, 1024 / 32), dim3(32, 8), 0, stream>>>(Wproj, wproj_t, 1024, 1024);

    gemm_bt<0><<<dim3(M_ / 128, 3072 / 128), 256, 0, stream>>>(
        x_bf, wqkv_t, bqkv, qkv, nullptr, M_, 3072, 1024);

    attn_kernel<<<dim3(T_ / 128, B_ * H_), 256, 0, stream>>>(
        qkv, qkv + (size_t)BHTD_, qkv + 2 * (size_t)BHTD_, ybuf);

    gemm_bt<1><<<dim3(M_ / 128, 1024 / 128), 256, 0, stream>>>(
        ybuf, wproj_t, bproj, nullptr, out, M_, 1024, 1024);
}